// Round 12
// baseline (42.041 us; speedup 1.0000x reference)
//
#include <hip/hip_runtime.h>
#include <math.h>
#include <stdint.h>

// Problem dims (fixed by reference setup_inputs)
#define BB 4
#define CC 8
#define PP 20
#define AA 30
#define SS 4
#define TT 2048
#define NB 18

#define TC 128                  // t-chunk (K-slab) per iteration
#define NCH (TT / TC)           // 16 chunks
#define PG 2                    // p's per block (both handled by EVERY wave)
#define NPG (PP / PG)           // 10 p-groups
#define WSTR 132                // f16 row stride: 264 B -> 2-row bank step 2 (2-way free)
#define WROWS 19                // rows 0..17 = W, row 18 = dump row for the unwrapped edge
#define NTH 256                 // 4 waves = 4 K-quarters; each does both p's

// Relaxed barrier: LDS-visibility only; global loads stay in flight across it.
#define BAR() do { asm volatile("s_waitcnt lgkmcnt(0)" ::: "memory"); \
                   __builtin_amdgcn_s_barrier(); } while (0)

typedef _Float16 half4_t __attribute__((ext_vector_type(4)));
typedef _Float16 half8_t __attribute__((ext_vector_type(8)));
typedef float f32x16 __attribute__((ext_vector_type(16)));

__device__ __forceinline__ void weight_top2(float x, int& n0, int& n1,
                                            float& w0, float& w1)
{
    const float PI_F  = 3.14159265358979323846f;
    const float INV_H = 2.8647913f;           // 18 / (2*pi)
    float u = (x + PI_F) * INV_H;             // in [0, 18]
    n0 = (int)floorf(u);
    n0 = n0 < 0 ? 0 : (n0 > NB - 1 ? NB - 1 : n0);
    float f  = u - (float)n0 - 0.5f;          // [-0.5, 0.5]
    float af = fabsf(f);
    n1 = n0 + (f >= 0.0f ? 1 : -1);
    float e;
    if (n1 < 0) {                             // reference's unwrapped low edge: w1 ~ 7e-16
        e = 0.0f; n1 = NB;                    // row 18 (never extracted)
    } else {
        if (n1 == NB) n1 = 0;                 // positive wrap: same gap formula
        // exp(-(H*(1-2af))*100) = exp(69.81317*af - 34.906585), folded
        e = __expf(fmaf(af, 69.81317008f, -34.90658504f));
    }
    w0 = __builtin_amdgcn_rcpf(1.0f + e);     // rel err ~1e-7 << f16 quantization
    w1 = 1.0f - w0;
}

// ---------------------------------------------------------------------------
// BARRIER-FREE main loop. Block = (bc, s, pg); wave kh owns t-columns
// [kh*32, kh*32+32) of every chunk for BOTH p tiles. Per chunk, per wave:
//   - B-fragments loaded DIRECTLY global->reg (32B/lane contiguous f32,
//     full-cache-line coalesced across the wave, L2-resident via XCD swizzle),
//     cvt f32->f16 in registers  -> NO ampT in LDS, NO staging, NO barriers.
//   - W scatter/unwrite/A-reads all within the wave's own columns (wave-
//     coherent LDS, compiler lgkmcnt ordering suffices).
// Waves free-run through all 16 chunks; only sync = one BAR before the
// epilogue merge of the 4 K-quarter partials. 20 waves/CU, 5 blocks/CU.
// ---------------------------------------------------------------------------
__global__ __launch_bounds__(NTH, 5)
void mi_fused_kernel(const float* __restrict__ phase,
                     const float* __restrict__ amp,
                     float* __restrict__ out)
{
    __shared__ __align__(16) _Float16 Wl[PG][WROWS * WSTR];  // 10,032 B
    __shared__ __align__(16) float    df[8 * 576];           // 18,432 B dump

    const int tid = threadIdx.x;
    // ---- XCD-aware swizzle (bijective 1280->1280): sharers of one amp slice
    //      land on one XCD (physical XCD ~ blockIdx%8 round-robin dispatch)
    const int bid = blockIdx.x;
    const int x   = bid & 7;                   // physical XCD
    const int kk  = bid >> 3;                  // 0..159
    const int pg  = kk % NPG;                  // member within amp-sharing group
    const int g   = x + 8 * (kk / NPG);        // 0..127 = bc*SS + s
    const int s   = g & (SS - 1);
    const int bc  = g >> 2;                    // b*CC + c

    const int kh   = tid >> 6;                 // wave = K-quarter (0..3)
    const int lane = tid & 63;
    const int mrow = lane & 31;
    const int mlh  = lane >> 5;
    const int arow = mrow < WROWS ? mrow : (WROWS - 1);  // A rows >=19 -> row 18 (bcast)
    const int brow = mrow < AA    ? mrow : (AA - 1);     // B rows 30,31 -> dup (unused)
    const int col  = kh * 32 + mrow;           // scatter: this lane's owned t-column
    _Float16* const ptile = &Wl[mlh][0];       // scatter: this lane's owned p tile

    // per-lane B pointer: row brow, chunk base + this wave/half's t offset
    const float* bp  = amp + (size_t)bc * (AA * SS * TT) + (size_t)s * TT
                           + (size_t)brow * (SS * TT) + kh * 32 + mlh * 8;
    // per-lane phase pointer: p = pg*PG + mlh, t-offset = col
    const float* phl = phase + ((size_t)(bc * PP + pg * PG + mlh) * SS + s) * TT + col;

    // ---- prologue: zero own columns of own tile (wave-local, no barrier) ----
    #pragma unroll
    for (int r = 0; r < WROWS; ++r)
        ptile[r * WSTR + col] = (_Float16)0.0f;
    float phv = phl[0];

    f32x16 acc0 = {}, acc1 = {};               // p0 / p1 accumulators
    int pn0 = 0, pn1 = 0;

    #pragma unroll 1
    for (int c = 0; c < NCH; ++c) {
        // ---- issue B-frag + next-phase global loads EARLY ----
        const float* bpc = bp + c * TC;
        float4 f00 = *(const float4*)(bpc);        // ks=0: t = kh*32 + mlh*8 + 0..3
        float4 f01 = *(const float4*)(bpc + 4);    //       +4..7
        float4 f10 = *(const float4*)(bpc + 16);   // ks=1: +16..19
        float4 f11 = *(const float4*)(bpc + 20);   //       +20..23
        float nphv = (c + 1 < NCH) ? phl[(c + 1) * TC] : 0.0f;

        // ---- unwrite previous chunk's entries, scatter this chunk's ----
        if (c > 0) {
            ptile[pn0 * WSTR + col] = (_Float16)0.0f;
            ptile[pn1 * WSTR + col] = (_Float16)0.0f;
        }
        {
            int n0, n1; float w0, w1;
            weight_top2(phv, n0, n1, w0, w1);
            ptile[n0 * WSTR + col] = (_Float16)w0;
            ptile[n1 * WSTR + col] = (_Float16)w1;
            pn0 = n0; pn1 = n1;
        }

        // ---- cvt B to f16 in registers (no LDS round-trip) ----
        half8_t bv0 = { (_Float16)f00.x, (_Float16)f00.y, (_Float16)f00.z, (_Float16)f00.w,
                        (_Float16)f01.x, (_Float16)f01.y, (_Float16)f01.z, (_Float16)f01.w };
        half8_t bv1 = { (_Float16)f10.x, (_Float16)f10.y, (_Float16)f10.z, (_Float16)f10.w,
                        (_Float16)f11.x, (_Float16)f11.y, (_Float16)f11.z, (_Float16)f11.w };

        // ---- 2 K-steps x 2 p: A-frags from own W cols, B from registers ----
        __builtin_amdgcn_s_setprio(1);
        #pragma unroll
        for (int ks = 0; ks < 2; ++ks) {
            int t0 = kh * 32 + ks * 16 + mlh * 8;
            const _Float16* A0b = &Wl[0][arow * WSTR + t0];
            const _Float16* A1b = &Wl[1][arow * WSTR + t0];
            half4_t p0a = *(const half4_t*)A0b;
            half4_t p0b = *(const half4_t*)(A0b + 4);
            half4_t p1a = *(const half4_t*)A1b;
            half4_t p1b = *(const half4_t*)(A1b + 4);
            half8_t a0v = __builtin_shufflevector(p0a, p0b, 0, 1, 2, 3, 4, 5, 6, 7);
            half8_t a1v = __builtin_shufflevector(p1a, p1b, 0, 1, 2, 3, 4, 5, 6, 7);
            half8_t bv  = ks ? bv1 : bv0;
            acc0 = __builtin_amdgcn_mfma_f32_32x32x16_f16(a0v, bv, acc0, 0, 0, 0);
            acc1 = __builtin_amdgcn_mfma_f32_32x32x16_f16(a1v, bv, acc1, 0, 0, 0);
        }
        __builtin_amdgcn_s_setprio(0);
        phv = nphv;
    }

    // ---- epilogue: dump [kh][pi][18][32] f32 partials (separate region) ----
    #pragma unroll
    for (int r = 0; r < 16; ++r) {
        int row = (r & 3) + 8 * (r >> 2) + 4 * mlh;   // HW-verified C/D layout
        if (row < NB) {
            df[(kh * 2 + 0) * 576 + row * 32 + mrow] = acc0[r];
            df[(kh * 2 + 1) * 576 + row * 32 + mrow] = acc1[r];
        }
    }
    BAR();   // the ONLY block-wide barrier: dump visible for the merge

    // waves 0,1: reduce 4 kh-partials for p = pg*PG + kh, entropy, store
    if (kh < PG && lane < AA) {
        float v[NB], tot = 0.0f;
        #pragma unroll
        for (int n = 0; n < NB; ++n) {
            v[n] = df[(0 * 2 + kh) * 576 + n * 32 + lane]
                 + df[(1 * 2 + kh) * 576 + n * 32 + lane]
                 + df[(2 * 2 + kh) * 576 + n * 32 + lane]
                 + df[(3 * 2 + kh) * 576 + n * 32 + lane];
            tot += v[n];
        }
        float inv = 1.0f / (tot + 1e-10f);
        float ne = 0.0f;
        #pragma unroll
        for (int n = 0; n < NB; ++n) {
            float pv = fmaxf(v[n] * inv, 1e-10f);
            ne += pv * logf(pv);
        }
        out[((size_t)(bc * SS + s) * PP + pg * PG + kh) * AA + lane] =
            1.0f + ne * 0.345975362f;          // 1/log(18)
    }
}

extern "C" void kernel_launch(void* const* d_in, const int* in_sizes, int n_in,
                              void* d_out, int out_size, void* d_ws, size_t ws_size,
                              hipStream_t stream)
{
    const float* phase = (const float*)d_in[0];
    const float* amp   = (const float*)d_in[1];
    float* out = (float*)d_out;
    hipLaunchKernelGGL(mi_fused_kernel, dim3(BB * CC * SS * NPG), dim3(NTH),
                       0, stream, phase, amp, out);
}

// Round 13
// 32.451 us; speedup vs baseline: 1.2955x; 1.2955x over previous
//
#include <hip/hip_runtime.h>
#include <math.h>
#include <stdint.h>

// Problem dims (fixed by reference setup_inputs)
#define BB 4
#define CC 8
#define PP 20
#define AA 30
#define SS 4
#define TT 2048
#define NB 18

#define TC 128                  // t-chunk (K-slab) per iteration
#define NCH (TT / TC)           // 16 chunks
#define PG 2                    // p's per block (both handled by EVERY wave)
#define NPG (PP / PG)           // 10 p-groups
#define WSTR 132                // f16 row stride: 264 B -> 2-row bank step 2 (2-way free)
#define WROWS 19                // rows 0..17 = W, row 18 = dump row for the unwrapped edge
#define NTH 256                 // 4 waves = 4 K-quarters; each does both p's

// Relaxed barrier: LDS-visibility only; global loads stay in flight across it.
#define BAR() do { asm volatile("s_waitcnt lgkmcnt(0)" ::: "memory"); \
                   __builtin_amdgcn_s_barrier(); } while (0)

typedef _Float16 half4_t __attribute__((ext_vector_type(4)));
typedef _Float16 half8_t __attribute__((ext_vector_type(8)));
typedef float f32x16 __attribute__((ext_vector_type(16)));

__device__ __forceinline__ void weight_top2(float x, int& n0, int& n1,
                                            float& w0, float& w1)
{
    const float PI_F  = 3.14159265358979323846f;
    const float INV_H = 2.8647913f;           // 18 / (2*pi)
    float u = (x + PI_F) * INV_H;             // in [0, 18]
    n0 = (int)floorf(u);
    n0 = n0 < 0 ? 0 : (n0 > NB - 1 ? NB - 1 : n0);
    float f  = u - (float)n0 - 0.5f;          // [-0.5, 0.5]
    float af = fabsf(f);
    n1 = n0 + (f >= 0.0f ? 1 : -1);
    float e;
    if (n1 < 0) {                             // reference's unwrapped low edge: w1 ~ 7e-16
        e = 0.0f; n1 = NB;                    // row 18 (never extracted)
    } else {
        if (n1 == NB) n1 = 0;                 // positive wrap: same gap formula
        // exp(-(H*(1-2af))*100) = exp(69.81317*af - 34.906585), folded
        e = __expf(fmaf(af, 69.81317008f, -34.90658504f));
    }
    w0 = __builtin_amdgcn_rcpf(1.0f + e);     // rel err ~1e-7 << f16 quantization
    w1 = 1.0f - w0;
}

// ---------------------------------------------------------------------------
// r11 structure with ROTATED software pipeline. Block = (bc, s, pg); wave kh
// owns t-cols [kh*32, kh*32+32) of every chunk for BOTH p tiles (B-frag
// reuse: 1 B-read feeds 2 MFMAs). Iteration order is rotated so the
// scatter->A-read dependency spans iterations:
//   { issue globals(c+1) | MFMA(c) on weights scattered LAST iter |
//     unwrite(c) + scatter(c+1) + stage-write(c+1) | BAR }
// Single W buffer is safe: W accesses are wave-internal and SIMT program
// order puts all MFMA reads of chunk c before any scatter write of c+1.
// ampT double-buffer is the only cross-wave state -> ONE relaxed BAR/chunk.
// 25.9 KB LDS, grid 1280 = exactly 5 blocks/CU, 20 waves/CU.
// XCD swizzle (verified r12: FETCH 25.6 MB): amp-slice sharers on one XCD.
// ---------------------------------------------------------------------------
__global__ __launch_bounds__(NTH, 5)
void mi_fused_kernel(const float* __restrict__ phase,
                     const float* __restrict__ amp,
                     float* __restrict__ out)
{
    // One arena: [Wl0 | Wl1 | ampT0 | ampT1] = 25,872 B (epilogue dump overlays)
    __shared__ __align__(16) _Float16 lds[2 * WROWS * WSTR + 2 * AA * WSTR];
    _Float16* const Wl0 = lds;
    _Float16* const Wl1 = lds + WROWS * WSTR;
    _Float16* const amp0 = lds + 2 * WROWS * WSTR;

    const int tid = threadIdx.x;
    // ---- XCD-aware swizzle (bijective 1280->1280): sharers of one amp slice
    //      land on one XCD (physical XCD ~ blockIdx%8 round-robin dispatch)
    const int bid = blockIdx.x;
    const int x   = bid & 7;                   // physical XCD
    const int kk  = bid >> 3;                  // 0..159
    const int pg  = kk % NPG;                  // member within amp-sharing group
    const int g   = x + 8 * (kk / NPG);        // 0..127 = bc*SS + s
    const int s   = g & (SS - 1);
    const int bc  = g >> 2;                    // b*CC + c

    const int kh   = tid >> 6;                 // wave = K-quarter (0..3)
    const int lane = tid & 63;
    const int mrow = lane & 31;
    const int mlh  = lane >> 5;
    const int arow = mrow < WROWS ? mrow : (WROWS - 1);  // A rows >=19 -> row 18 (bcast)
    const int brow = mrow < AA    ? mrow : (AA - 1);     // B rows 30,31 -> dup (unused)
    const int col  = kh * 32 + mrow;           // scatter: this lane's owned t-column
    _Float16* const ptile = mlh ? Wl1 : Wl0;   // scatter: this lane's owned p tile

    const float* am  = amp + (size_t)bc * (AA * SS * TT) + (size_t)s * TT;
    // per-lane phase pointer: p = pg*PG + mlh, t-offset = col
    const float* phl = phase + ((size_t)(bc * PP + pg * PG + mlh) * SS + s) * TT + col;

    // ---- prologue: per-lane zero own cols (wave-local), scatter chunk 0,
    //      cooperative stage of chunk 0, one BAR ----
    #pragma unroll
    for (int r = 0; r < WROWS; ++r)
        ptile[r * WSTR + col] = (_Float16)0.0f;

    int pn0, pn1;
    {
        float phv = phl[0];
        int n0, n1; float w0, w1;
        weight_top2(phv, n0, n1, w0, w1);
        ptile[n0 * WSTR + col] = (_Float16)w0;
        ptile[n1 * WSTR + col] = (_Float16)w1;
        pn0 = n0; pn1 = n1;
    }
    #pragma unroll
    for (int j = 0; j < 4; ++j) {              // stage chunk 0: 960 quads, coop
        int q = tid + j * NTH;
        int a = q >> 5, tq = q & 31;           // 32 quads per row (TC/4)
        if (a < AA) {
            const float4 v = *(const float4*)&am[(size_t)a * (SS * TT) + tq * 4];
            half4_t h = { (_Float16)v.x, (_Float16)v.y, (_Float16)v.z, (_Float16)v.w };
            *(half4_t*)&amp0[a * WSTR + tq * 4] = h;
        }
    }
    BAR();

    f32x16 acc0 = {}, acc1 = {};               // p0 / p1 accumulators

    #pragma unroll 1
    for (int c = 0; c < NCH; ++c) {
        const int cb = c & 1, tb = cb ^ 1;
        const _Float16* aB = amp0 + cb * (AA * WSTR);
        _Float16* aW = amp0 + tb * (AA * WSTR);

        // ---- issue next-chunk global loads EARLY ----
        float nphv = 0.0f;
        float4 stg[4];
        if (c + 1 < NCH) {
            nphv = phl[(c + 1) * TC];
            #pragma unroll
            for (int j = 0; j < 4; ++j) {
                int q = tid + j * NTH;
                int a = q >> 5, tq = q & 31;
                int ac = a < AA ? a : (AA - 1);          // clamp: no OOB read
                stg[j] = *(const float4*)&am[(size_t)ac * (SS * TT) + (c + 1) * TC + tq * 4];
            }
        }

        // ---- MFMA chunk c: weights were scattered LAST iteration ----
        __builtin_amdgcn_s_setprio(1);
        #pragma unroll
        for (int ks = 0; ks < 2; ++ks) {
            int t0 = kh * 32 + ks * 16 + mlh * 8;
            const _Float16* Bb  = aB  + brow * WSTR + t0;
            const _Float16* A0b = Wl0 + arow * WSTR + t0;
            const _Float16* A1b = Wl1 + arow * WSTR + t0;
            half4_t b0 = *(const half4_t*)Bb;
            half4_t b1 = *(const half4_t*)(Bb + 4);
            half4_t p0a = *(const half4_t*)A0b;
            half4_t p0b = *(const half4_t*)(A0b + 4);
            half4_t p1a = *(const half4_t*)A1b;
            half4_t p1b = *(const half4_t*)(A1b + 4);
            half8_t bv  = __builtin_shufflevector(b0, b1, 0, 1, 2, 3, 4, 5, 6, 7);
            half8_t a0v = __builtin_shufflevector(p0a, p0b, 0, 1, 2, 3, 4, 5, 6, 7);
            half8_t a1v = __builtin_shufflevector(p1a, p1b, 0, 1, 2, 3, 4, 5, 6, 7);
            acc0 = __builtin_amdgcn_mfma_f32_32x32x16_f16(a0v, bv, acc0, 0, 0, 0);
            acc1 = __builtin_amdgcn_mfma_f32_32x32x16_f16(a1v, bv, acc1, 0, 0, 0);
        }
        __builtin_amdgcn_s_setprio(0);

        // ---- prepare chunk c+1: unwrite c, scatter c+1, stage-write c+1 ----
        // (after the MFMA reads in program order -> single W buffer is safe;
        //  the scatter->read dependency is now resolved across the BAR)
        if (c + 1 < NCH) {
            ptile[pn0 * WSTR + col] = (_Float16)0.0f;
            ptile[pn1 * WSTR + col] = (_Float16)0.0f;
            int n0, n1; float w0, w1;
            weight_top2(nphv, n0, n1, w0, w1);
            ptile[n0 * WSTR + col] = (_Float16)w0;
            ptile[n1 * WSTR + col] = (_Float16)w1;
            pn0 = n0; pn1 = n1;
            #pragma unroll
            for (int j = 0; j < 4; ++j) {
                int q = tid + j * NTH;
                int a = q >> 5, tq = q & 31;
                if (a < AA) {
                    half4_t h = { (_Float16)stg[j].x, (_Float16)stg[j].y,
                                  (_Float16)stg[j].z, (_Float16)stg[j].w };
                    *(half4_t*)&aW[a * WSTR + tq * 4] = h;
                }
            }
        }
        BAR();   // ampT: my reads of [cb] done; staging writes to [tb] visible
    }

    // ---- epilogue: dump [kh][pi][18][32] f32 partials over the arena ----
    float* const df = (float*)lds;             // 8 x 576 f32 = 18,432 B < 25,872 B
    #pragma unroll
    for (int r = 0; r < 16; ++r) {
        int row = (r & 3) + 8 * (r >> 2) + 4 * mlh;   // HW-verified C/D layout
        if (row < NB) {
            df[(kh * 2 + 0) * 576 + row * 32 + mrow] = acc0[r];
            df[(kh * 2 + 1) * 576 + row * 32 + mrow] = acc1[r];
        }
    }
    BAR();

    // waves 0,1: reduce 4 kh-partials for p = pg*PG + kh, entropy, store
    if (kh < PG && lane < AA) {
        float v[NB], tot = 0.0f;
        #pragma unroll
        for (int n = 0; n < NB; ++n) {
            v[n] = df[(0 * 2 + kh) * 576 + n * 32 + lane]
                 + df[(1 * 2 + kh) * 576 + n * 32 + lane]
                 + df[(2 * 2 + kh) * 576 + n * 32 + lane]
                 + df[(3 * 2 + kh) * 576 + n * 32 + lane];
            tot += v[n];
        }
        float inv = 1.0f / (tot + 1e-10f);
        float ne = 0.0f;
        #pragma unroll
        for (int n = 0; n < NB; ++n) {
            float pv = fmaxf(v[n] * inv, 1e-10f);
            ne += pv * logf(pv);
        }
        out[((size_t)(bc * SS + s) * PP + pg * PG + kh) * AA + lane] =
            1.0f + ne * 0.345975362f;          // 1/log(18)
    }
}

extern "C" void kernel_launch(void* const* d_in, const int* in_sizes, int n_in,
                              void* d_out, int out_size, void* d_ws, size_t ws_size,
                              hipStream_t stream)
{
    const float* phase = (const float*)d_in[0];
    const float* amp   = (const float*)d_in[1];
    float* out = (float*)d_out;
    hipLaunchKernelGGL(mi_fused_kernel, dim3(BB * CC * SS * NPG), dim3(NTH),
                       0, stream, phase, amp, out);
}